// Round 3
// baseline (920.882 us; speedup 1.0000x reference)
//
#include <hip/hip_runtime.h>
#include <cstdint>
#include <cstddef>

typedef __attribute__((ext_vector_type(8))) short short8;
typedef __attribute__((ext_vector_type(4))) float floatx4;
typedef unsigned short u16;
typedef unsigned long long u64;

union FragAB { short8 s; u64 q[2]; };
struct L16 { u64 lo, hi; };

__device__ __forceinline__ float bf2f(u16 u) {
  union { unsigned int i; float f; } v; v.i = ((unsigned int)u) << 16; return v.f;
}
__device__ __forceinline__ u16 f2bf(float f) {
  union { float f; unsigned int u; } v; v.f = f;
  return (u16)((v.u + 0x7fffu + ((v.u >> 16) & 1u)) >> 16);
}
__device__ __forceinline__ void bfp(unsigned int p, float& x, float& y) {
  union { unsigned int i; float f; } a, b;
  a.i = p << 16; b.i = p & 0xffff0000u;
  x = a.f; y = b.f;
}
__device__ __forceinline__ unsigned int packbf(float a, float b) {
  return (unsigned int)f2bf(a) | ((unsigned int)f2bf(b) << 16);
}
__device__ __forceinline__ u64 pack4(float a, float b, float c, float d) {
  return (u64)f2bf(a) | ((u64)f2bf(b) << 16) | ((u64)f2bf(c) << 32) | ((u64)f2bf(d) << 48);
}

// ---------------- DCT-II orthonormal 56x56 matrix (fp32) ----------------
__global__ __launch_bounds__(256) void k_dctmat(float* __restrict__ Wd) {
  int i = blockIdx.x * 256 + threadIdx.x;
  if (i < 56 * 56) {
    int n = i / 56, x = i - n * 56;
    float v = cosf(3.14159265358979323846f * (float)n * ((float)x + 0.5f) / 56.0f)
              * 0.1889822365046136f;            // sqrt(2/56)
    if (n == 0) v *= 0.7071067811865476f;
    Wd[i] = v;
  }
}

// ---------------- depthwise conv 3x3, NCHW fp32 -> channel-last bf16 ----------------
__global__ __launch_bounds__(256) void k_conv(const float* __restrict__ x,
                                              const float* __restrict__ w9,
                                              const float* __restrict__ b1,
                                              u16* __restrict__ hbf) {
  __shared__ float xs[64 * 177];  // [c][3 rows][59 cols], col 0 <-> gx=-1
  const int y = blockIdx.x, c0 = blockIdx.y * 64, b = blockIdx.z;
  const int tid = threadIdx.x, cl = tid & 63, wv = tid >> 6;
  float wr[9];
  #pragma unroll
  for (int k = 0; k < 9; ++k) wr[k] = w9[(c0 + cl) * 9 + k];
  const float br = b1[c0 + cl];
  for (int it = 0; it < 48; ++it) {
    int combo = it * 4 + wv;             // 0..191 -> (c, r)
    int c = combo / 3, r = combo - c * 3;
    int col = tid & 63;
    if (col < 58) {
      int gy = y + r - 1, gx = col - 1;
      float v = 0.f;
      if (gy >= 0 && gy < 56 && gx >= 0 && gx < 56)
        v = x[(((size_t)b * 384 + c0 + c) * 56 + gy) * 56 + gx];
      xs[c * 177 + r * 59 + col] = v;
    }
  }
  __syncthreads();
  for (int it = 0; it < 14; ++it) {
    int px = it * 4 + wv;
    float a = br;
    #pragma unroll
    for (int dy = 0; dy < 3; ++dy)
      #pragma unroll
      for (int dx = 0; dx < 3; ++dx)
        a += wr[dy * 3 + dx] * xs[cl * 177 + dy * 59 + px + dx];
    hbf[((size_t)b * 3136 + y * 56 + px) * 384 + c0 + cl] = f2bf(a);
  }
}

// ---------------- MFMA mainloop: C[m][n] = sum_k A[m,k]*B[n,k], K=384 ----------------
// AF32/BF32: source is fp32 (convert to bf16 during LDS staging) else bf16.
#define LDA 68
template<bool AF32, bool BF32>
__device__ __forceinline__ void gemm_ml(const void* __restrict__ Ap,
                                        const void* __restrict__ Bp,
                                        int m0, int n0,
                                        u16* As, u16* Bs,
                                        floatx4 acc[4][4]) {
  const int tid  = threadIdx.x;
  const int lane = tid & 63;
  const int wv   = tid >> 6;
  const int wm   = wv & 1, wn = wv >> 1;
  const int q    = lane >> 4, l15 = lane & 15;
  const int srow = tid >> 3, sc8 = tid & 7;   // 8 threads/row, 32 rows/pass
  for (int kt = 0; kt < 384; kt += 64) {
    __syncthreads();
    #pragma unroll
    for (int p = 0; p < 4; ++p) {
      int row = srow + p * 32;
      if constexpr (AF32) {
        const float4* s = (const float4*)((const float*)Ap + (size_t)(m0 + row) * 384 + kt + sc8 * 8);
        float4 v0 = s[0], v1 = s[1];
        *(u64*)&As[row * LDA + sc8 * 8]     = pack4(v0.x, v0.y, v0.z, v0.w);
        *(u64*)&As[row * LDA + sc8 * 8 + 4] = pack4(v1.x, v1.y, v1.z, v1.w);
      } else {
        L16 va = *(const L16*)((const u16*)Ap + (size_t)(m0 + row) * 384 + kt + sc8 * 8);
        *(u64*)&As[row * LDA + sc8 * 8]     = va.lo;
        *(u64*)&As[row * LDA + sc8 * 8 + 4] = va.hi;
      }
      if constexpr (BF32) {
        const float4* s = (const float4*)((const float*)Bp + (size_t)(n0 + row) * 384 + kt + sc8 * 8);
        float4 v0 = s[0], v1 = s[1];
        *(u64*)&Bs[row * LDA + sc8 * 8]     = pack4(v0.x, v0.y, v0.z, v0.w);
        *(u64*)&Bs[row * LDA + sc8 * 8 + 4] = pack4(v1.x, v1.y, v1.z, v1.w);
      } else {
        L16 vb = *(const L16*)((const u16*)Bp + (size_t)(n0 + row) * 384 + kt + sc8 * 8);
        *(u64*)&Bs[row * LDA + sc8 * 8]     = vb.lo;
        *(u64*)&Bs[row * LDA + sc8 * 8 + 4] = vb.hi;
      }
    }
    __syncthreads();
    #pragma unroll
    for (int kc = 0; kc < 64; kc += 32) {
      FragAB af[4], bf[4];
      #pragma unroll
      for (int i = 0; i < 4; ++i) {
        int ra = (wm * 64 + i * 16 + l15) * LDA + kc + q * 8;
        af[i].q[0] = *(const u64*)&As[ra];
        af[i].q[1] = *(const u64*)&As[ra + 4];
        int rb = (wn * 64 + i * 16 + l15) * LDA + kc + q * 8;
        bf[i].q[0] = *(const u64*)&Bs[rb];
        bf[i].q[1] = *(const u64*)&Bs[rb + 4];
      }
      #pragma unroll
      for (int i = 0; i < 4; ++i)
        #pragma unroll
        for (int j = 0; j < 4; ++j)
          acc[i][j] = __builtin_amdgcn_mfma_f32_16x16x32_bf16(af[i].s, bf[j].s, acc[i][j], 0, 0, 0);
    }
  }
}

#define GEMM_PROLOGUE() \
  __shared__ __align__(16) u16 As[128 * LDA]; \
  __shared__ __align__(16) u16 Bs[128 * LDA]; \
  floatx4 acc[4][4]; \
  { floatx4 zv = {0.f, 0.f, 0.f, 0.f}; \
    _Pragma("unroll") for (int i = 0; i < 4; ++i) \
      _Pragma("unroll") for (int j = 0; j < 4; ++j) acc[i][j] = zv; } \
  const int lane = threadIdx.x & 63, wv = threadIdx.x >> 6; \
  const int wm = wv & 1, wn = wv >> 1, q = lane >> 4, l15 = lane & 15;

// GEMM1: h(bf16) @ lin_w^T(fp32) + lin_b -> xx (n<384), z (n>=384), bf16 channel-last
__global__ __launch_bounds__(256) void k_gemm_lin(const u16* __restrict__ A,
                                                  const float* __restrict__ Bw,
                                                  const float* __restrict__ bias,
                                                  u16* __restrict__ xx, u16* __restrict__ z) {
  GEMM_PROLOGUE();
  int m0 = blockIdx.x * 128, n0 = blockIdx.y * 128;
  gemm_ml<false, true>(A, Bw, m0, n0, As, Bs, acc);
  #pragma unroll
  for (int i = 0; i < 4; ++i)
    #pragma unroll
    for (int j = 0; j < 4; ++j) {
      int n = n0 + wn * 64 + j * 16 + l15;
      float bb = bias[n];
      #pragma unroll
      for (int r = 0; r < 4; ++r) {
        int m = m0 + wm * 64 + i * 16 + q * 4 + r;
        float v = acc[i][j][r] + bb;
        if (n < 384) xx[(size_t)m * 384 + n] = f2bf(v);
        else         z[(size_t)m * 384 + (n - 384)] = f2bf(v);
      }
    }
}

// GEMM2: freq_embed(fp32) @ tok_w^T(fp32) + tok_b -> gelu -> wave gain g (bf16)
__global__ __launch_bounds__(256) void k_gemm_tok(const float* __restrict__ A,
                                                  const float* __restrict__ Bw,
                                                  const float* __restrict__ bias,
                                                  const float* __restrict__ cs,
                                                  const float* __restrict__ al,
                                                  u16* __restrict__ g) {
  GEMM_PROLOGUE();
  int m0 = blockIdx.x * 128, n0 = blockIdx.y * 128;
  gemm_ml<true, true>(A, Bw, m0, n0, As, Bs, acc);
  const float c0 = cs[0], a0 = al[0];
  const float sc = (1.0f / (c0 + 1e-8f)) * (1.0f + 0.5f * a0);
  #pragma unroll
  for (int i = 0; i < 4; ++i)
    #pragma unroll
    for (int j = 0; j < 4; ++j) {
      int n = n0 + wn * 64 + j * 16 + l15;
      float bb = bias[n];
      #pragma unroll
      for (int r = 0; r < 4; ++r) {
        int m = m0 + wm * 64 + i * 16 + q * 4 + r;
        float v = acc[i][j][r] + bb;
        float t = 0.5f * v * (1.0f + erff(v * 0.7071067811865476f));  // exact gelu
        float ct = c0 * t;
        g[(size_t)m * 384 + n] = f2bf(cosf(ct) + sinf(ct) * sc);
      }
    }
}

// GEMM3: out_w(fp32, M=channel) x A3(bf16, N=pixel) -> d_out[b,c,h,w] fp32 + out_b
__global__ __launch_bounds__(256) void k_gemm_out(const float* __restrict__ A,
                                                  const u16* __restrict__ Bp,
                                                  const float* __restrict__ bias,
                                                  float* __restrict__ outp) {
  GEMM_PROLOGUE();
  int m0 = blockIdx.x * 128, n0 = blockIdx.y * 128;
  gemm_ml<true, false>(A, Bp, m0, n0, As, Bs, acc);
  #pragma unroll
  for (int i = 0; i < 4; ++i)
    #pragma unroll
    for (int j = 0; j < 4; ++j) {
      int t = n0 + wn * 64 + j * 16 + l15;      // pixel index
      int b = t / 3136, p = t - b * 3136;
      #pragma unroll
      for (int r = 0; r < 4; ++r) {
        int m = m0 + wm * 64 + i * 16 + q * 4 + r;   // channel
        outp[((size_t)b * 384 + m) * 3136 + p] = acc[i][j][r] + bias[m];
      }
    }
}

// ---------------- DCT chain (fp32 math, bf16 storage, in-place) ----------------
// xx[b,h,w,c] -> u1[b,n,w,c] = sum_h Wd[n,h]*xx  (in-place)
__global__ __launch_bounds__(256) void k_dct_h(u16* __restrict__ xx,
                                               const float* __restrict__ Wd) {
  __shared__ float Xs[56 * 128];
  __shared__ float Ws[3136];
  const int w = blockIdx.x, cb = blockIdx.y * 128, b = blockIdx.z;
  const int tid = threadIdx.x;
  for (int i = tid; i < 3136; i += 256) Ws[i] = Wd[i];
  for (int i = tid; i < 56 * 64; i += 256) {
    int h = i >> 6, cu = i & 63;
    unsigned int p = *(const unsigned int*)(xx + ((size_t)(b * 56 + h) * 56 + w) * 384 + cb + cu * 2);
    bfp(p, Xs[h * 128 + cu * 2], Xs[h * 128 + cu * 2 + 1]);
  }
  __syncthreads();
  const int lane = tid & 63, wv = tid >> 6;
  float a0[14], a1[14];
  #pragma unroll
  for (int k = 0; k < 14; ++k) { a0[k] = 0.f; a1[k] = 0.f; }
  for (int h = 0; h < 56; ++h) {
    float x0 = Xs[h * 128 + 2 * lane];
    float x1 = Xs[h * 128 + 2 * lane + 1];
    #pragma unroll
    for (int k = 0; k < 14; ++k) {
      float wn = Ws[(wv + 4 * k) * 56 + h];
      a0[k] += wn * x0; a1[k] += wn * x1;
    }
  }
  #pragma unroll
  for (int k = 0; k < 14; ++k) {
    int n = wv + 4 * k;
    *(unsigned int*)(xx + ((size_t)(b * 56 + n) * 56 + w) * 384 + cb + 2 * lane) = packbf(a0[k], a1[k]);
  }
}

// fused: V = Wd @ u1[b,n] (over w); V *= g; y1[b,n] = Wd^T @ V (over m). In-place on u1.
__global__ __launch_bounds__(256) void k_mid(u16* __restrict__ u1,
                                             const u16* __restrict__ g,
                                             const float* __restrict__ Wd) {
  __shared__ float Us[56 * 64];
  __shared__ float Vs[56 * 64];
  __shared__ float Ws[3136];
  const int n = blockIdx.x, cb = blockIdx.y * 64, b = blockIdx.z;
  const int tid = threadIdx.x;
  for (int i = tid; i < 3136; i += 256) Ws[i] = Wd[i];
  for (int i = tid; i < 56 * 32; i += 256) {
    int ww = i >> 5, cu = i & 31;
    unsigned int p = *(const unsigned int*)(u1 + ((size_t)(b * 56 + n) * 56 + ww) * 384 + cb + cu * 2);
    bfp(p, Us[ww * 64 + cu * 2], Us[ww * 64 + cu * 2 + 1]);
  }
  __syncthreads();
  const int lane = tid & 63, wv = tid >> 6;
  {
    float a[14];
    #pragma unroll
    for (int k = 0; k < 14; ++k) a[k] = 0.f;
    for (int ww = 0; ww < 56; ++ww) {
      float xv = Us[ww * 64 + lane];
      #pragma unroll
      for (int k = 0; k < 14; ++k)
        a[k] += Ws[(wv + 4 * k) * 56 + ww] * xv;
    }
    #pragma unroll
    for (int k = 0; k < 14; ++k) Vs[(wv + 4 * k) * 64 + lane] = a[k];
  }
  __syncthreads();
  for (int i = tid; i < 56 * 32; i += 256) {
    int m = i >> 5, cu = i & 31;
    unsigned int p = *(const unsigned int*)(g + ((size_t)(b * 56 + n) * 56 + m) * 384 + cb + cu * 2);
    float g0, g1; bfp(p, g0, g1);
    Vs[m * 64 + cu * 2]     *= g0;
    Vs[m * 64 + cu * 2 + 1] *= g1;
  }
  __syncthreads();
  {
    float a[14];
    #pragma unroll
    for (int k = 0; k < 14; ++k) a[k] = 0.f;
    for (int m = 0; m < 56; ++m) {
      float xv = Vs[m * 64 + lane];
      #pragma unroll
      for (int k = 0; k < 14; ++k)
        a[k] += Ws[m * 56 + (wv + 4 * k)] * xv;   // Wd[m, yy]
    }
    #pragma unroll
    for (int k = 0; k < 14; ++k) {
      int yy = wv + 4 * k;
      u1[((size_t)(b * 56 + n) * 56 + yy) * 384 + cb + lane] = f2bf(a[k]);
    }
  }
}

// y1[b,n,yy,c] -> y2[b,x,yy,c] = sum_n Wd[n,x]*y1  (in-place)
__global__ __launch_bounds__(256) void k_idct_h(u16* __restrict__ y1,
                                                const float* __restrict__ Wd) {
  __shared__ float Ys[56 * 128];
  __shared__ float Ws[3136];
  const int yy = blockIdx.x, cb = blockIdx.y * 128, b = blockIdx.z;
  const int tid = threadIdx.x;
  for (int i = tid; i < 3136; i += 256) Ws[i] = Wd[i];
  for (int i = tid; i < 56 * 64; i += 256) {
    int nn = i >> 6, cu = i & 63;
    unsigned int p = *(const unsigned int*)(y1 + ((size_t)(b * 56 + nn) * 56 + yy) * 384 + cb + cu * 2);
    bfp(p, Ys[nn * 128 + cu * 2], Ys[nn * 128 + cu * 2 + 1]);
  }
  __syncthreads();
  const int lane = tid & 63, wv = tid >> 6;
  float a0[14], a1[14];
  #pragma unroll
  for (int k = 0; k < 14; ++k) { a0[k] = 0.f; a1[k] = 0.f; }
  for (int nn = 0; nn < 56; ++nn) {
    float x0 = Ys[nn * 128 + 2 * lane];
    float x1 = Ys[nn * 128 + 2 * lane + 1];
    #pragma unroll
    for (int k = 0; k < 14; ++k) {
      float wn = Ws[nn * 56 + (wv + 4 * k)];   // Wd[n, x]
      a0[k] += wn * x0; a1[k] += wn * x1;
    }
  }
  #pragma unroll
  for (int k = 0; k < 14; ++k) {
    int x = wv + 4 * k;
    *(unsigned int*)(y1 + ((size_t)(b * 56 + x) * 56 + yy) * 384 + cb + 2 * lane) = packbf(a0[k], a1[k]);
  }
}

// ---------------- LayerNorm + SiLU gate -> bf16 A3 (in-place over y2) ----------------
__global__ __launch_bounds__(256) void k_ln(u16* __restrict__ y2,
                                            const u16* __restrict__ z,
                                            const float* __restrict__ lgm,
                                            const float* __restrict__ lbt) {
  const int t = blockIdx.x * 4 + (threadIdx.x >> 6);
  const int lane = threadIdx.x & 63;
  u16* yr = y2 + (size_t)t * 384;
  const u16* zr = z + (size_t)t * 384;
  float v[6]; float s = 0.f, s2 = 0.f;
  #pragma unroll
  for (int k = 0; k < 3; ++k) {
    unsigned int p = *(const unsigned int*)(yr + 2 * lane + 128 * k);
    float f0, f1; bfp(p, f0, f1);
    v[2 * k] = f0; v[2 * k + 1] = f1;
    s += f0 + f1; s2 += f0 * f0 + f1 * f1;
  }
  #pragma unroll
  for (int off = 32; off >= 1; off >>= 1) {
    s  += __shfl_xor(s, off, 64);
    s2 += __shfl_xor(s2, off, 64);
  }
  const float mu  = s * (1.0f / 384.0f);
  const float var = s2 * (1.0f / 384.0f) - mu * mu;
  const float inv = rsqrtf(var + 1e-5f);
  #pragma unroll
  for (int k = 0; k < 3; ++k) {
    int c = 2 * lane + 128 * k;
    float z0, z1;
    bfp(*(const unsigned int*)(zr + c), z0, z1);
    float yn0 = (v[2 * k]     - mu) * inv * lgm[c]     + lbt[c];
    float yn1 = (v[2 * k + 1] - mu) * inv * lgm[c + 1] + lbt[c + 1];
    float ga0 = z0 / (1.0f + expf(-z0));
    float ga1 = z1 / (1.0f + expf(-z1));
    *(unsigned int*)(yr + c) = packbf(yn0 * ga0, yn1 * ga1);
  }
}

// ---------------- launch ----------------
extern "C" void kernel_launch(void* const* d_in, const int* in_sizes, int n_in,
                              void* d_out, int out_size, void* d_ws, size_t ws_size,
                              hipStream_t stream) {
  const float* x     = (const float*)d_in[0];
  const float* fe    = (const float*)d_in[1];
  const float* dw_w  = (const float*)d_in[2];
  const float* dw_b  = (const float*)d_in[3];
  const float* lin_w = (const float*)d_in[4];
  const float* lin_b = (const float*)d_in[5];
  const float* tok_w = (const float*)d_in[6];
  const float* tok_b = (const float*)d_in[7];
  const float* ln_g  = (const float*)d_in[8];
  const float* ln_b  = (const float*)d_in[9];
  const float* out_w = (const float*)d_in[10];
  const float* out_b = (const float*)d_in[11];
  const float* cs    = (const float*)d_in[12];
  const float* al    = (const float*)d_in[13];
  float* outp = (float*)d_out;
  char* ws = (char*)d_ws;

  // workspace: Wd (fp32) + 3 bf16 slots of 50176*384 = 38,535,168 B. Total 115,621,888 B
  // (same footprint round 2 proved mapped).
  float* Wd = (float*)(ws + 0);                        // 12,544 B
  u16* SA = (u16*)(ws + 16384);                        // h, then g
  u16* SB = (u16*)(ws + 16384 + 38535168);             // xx -> u1 -> y1 -> y2 -> A3 (in-place chain)
  u16* SC = (u16*)(ws + 16384 + 2 * (size_t)38535168); // z

  k_dctmat<<<dim3(13), dim3(256), 0, stream>>>(Wd);
  k_conv<<<dim3(56, 6, 16), dim3(256), 0, stream>>>(x, dw_w, dw_b, SA);          // h in SA
  k_gemm_lin<<<dim3(392, 6), dim3(256), 0, stream>>>(SA, lin_w, lin_b, SB, SC);  // xx in SB, z in SC
  k_gemm_tok<<<dim3(392, 3), dim3(256), 0, stream>>>(fe, tok_w, tok_b, cs, al, SA); // g in SA
  k_dct_h<<<dim3(56, 3, 16), dim3(256), 0, stream>>>(SB, Wd);                    // xx -> u1
  k_mid<<<dim3(56, 6, 16), dim3(256), 0, stream>>>(SB, SA, Wd);                  // u1,g -> y1
  k_idct_h<<<dim3(56, 3, 16), dim3(256), 0, stream>>>(SB, Wd);                   // y1 -> y2
  k_ln<<<dim3(12544), dim3(256), 0, stream>>>(SB, SC, ln_g, ln_b);               // y2,z -> A3
  k_gemm_out<<<dim3(3, 392), dim3(256), 0, stream>>>(out_w, SB, out_b, outp);
}

// Round 4
// 919.741 us; speedup vs baseline: 1.0012x; 1.0012x over previous
//
#include <hip/hip_runtime.h>
#include <cstdint>
#include <cstddef>

typedef __attribute__((ext_vector_type(8))) short short8;
typedef __attribute__((ext_vector_type(4))) float floatx4;
typedef unsigned short u16;
typedef unsigned long long u64;

union FragAB { short8 s; u64 q[2]; };
struct L16 { u64 lo, hi; };

__device__ __forceinline__ float bf2f(u16 u) {
  union { unsigned int i; float f; } v; v.i = ((unsigned int)u) << 16; return v.f;
}
__device__ __forceinline__ u16 f2bf(float f) {
  union { float f; unsigned int u; } v; v.f = f;
  return (u16)((v.u + 0x7fffu + ((v.u >> 16) & 1u)) >> 16);
}
__device__ __forceinline__ void bfp(unsigned int p, float& x, float& y) {
  union { unsigned int i; float f; } a, b;
  a.i = p << 16; b.i = p & 0xffff0000u;
  x = a.f; y = b.f;
}
__device__ __forceinline__ unsigned int packbf(float a, float b) {
  return (unsigned int)f2bf(a) | ((unsigned int)f2bf(b) << 16);
}
__device__ __forceinline__ u64 pack4(float a, float b, float c, float d) {
  return (u64)f2bf(a) | ((u64)f2bf(b) << 16) | ((u64)f2bf(c) << 32) | ((u64)f2bf(d) << 48);
}

// ---------------- DCT-II orthonormal 56x56 matrix (fp32) ----------------
__global__ __launch_bounds__(256) void k_dctmat(float* __restrict__ Wd) {
  int i = blockIdx.x * 256 + threadIdx.x;
  if (i < 56 * 56) {
    int n = i / 56, x = i - n * 56;
    float v = cosf(3.14159265358979323846f * (float)n * ((float)x + 0.5f) / 56.0f)
              * 0.1889822365046136f;            // sqrt(2/56)
    if (n == 0) v *= 0.7071067811865476f;
    Wd[i] = v;
  }
}

// ---------------- depthwise conv 3x3, NCHW fp32 -> channel-last bf16 ----------------
__global__ __launch_bounds__(256) void k_conv(const float* __restrict__ x,
                                              const float* __restrict__ w9,
                                              const float* __restrict__ b1,
                                              u16* __restrict__ hbf) {
  __shared__ float xs[64 * 177];  // [c][3 rows][59 cols], col 0 <-> gx=-1
  const int y = blockIdx.x, c0 = blockIdx.y * 64, b = blockIdx.z;
  const int tid = threadIdx.x, cl = tid & 63, wv = tid >> 6;
  float wr[9];
  #pragma unroll
  for (int k = 0; k < 9; ++k) wr[k] = w9[(c0 + cl) * 9 + k];
  const float br = b1[c0 + cl];
  for (int it = 0; it < 48; ++it) {
    int combo = it * 4 + wv;             // 0..191 -> (c, r)
    int c = combo / 3, r = combo - c * 3;
    int col = tid & 63;
    if (col < 58) {
      int gy = y + r - 1, gx = col - 1;
      float v = 0.f;
      if (gy >= 0 && gy < 56 && gx >= 0 && gx < 56)
        v = x[(((size_t)b * 384 + c0 + c) * 56 + gy) * 56 + gx];
      xs[c * 177 + r * 59 + col] = v;
    }
  }
  __syncthreads();
  for (int it = 0; it < 14; ++it) {
    int px = it * 4 + wv;
    float a = br;
    #pragma unroll
    for (int dy = 0; dy < 3; ++dy)
      #pragma unroll
      for (int dx = 0; dx < 3; ++dx)
        a += wr[dy * 3 + dx] * xs[cl * 177 + dy * 59 + px + dx];
    hbf[((size_t)b * 3136 + y * 56 + px) * 384 + c0 + cl] = f2bf(a);
  }
}

// ---------------- MFMA mainloop: C[m][n] = sum_k A[m,k]*B[n,k], K=384 ----------------
#define LDA 68
#define TS 132   // epilogue LDS tile stride (u16); 128*132*2 = 33792 B <= 34816 B
template<bool AF32, bool BF32>
__device__ __forceinline__ void gemm_ml(const void* __restrict__ Ap,
                                        const void* __restrict__ Bp,
                                        int m0, int n0,
                                        u16* As, u16* Bs,
                                        floatx4 acc[4][4]) {
  const int tid  = threadIdx.x;
  const int lane = tid & 63;
  const int wv   = tid >> 6;
  const int wm   = wv & 1, wn = wv >> 1;
  const int q    = lane >> 4, l15 = lane & 15;
  const int srow = tid >> 3, sc8 = tid & 7;   // 8 threads/row, 32 rows/pass
  for (int kt = 0; kt < 384; kt += 64) {
    __syncthreads();
    #pragma unroll
    for (int p = 0; p < 4; ++p) {
      int row = srow + p * 32;
      if constexpr (AF32) {
        const float4* s = (const float4*)((const float*)Ap + (size_t)(m0 + row) * 384 + kt + sc8 * 8);
        float4 v0 = s[0], v1 = s[1];
        *(u64*)&As[row * LDA + sc8 * 8]     = pack4(v0.x, v0.y, v0.z, v0.w);
        *(u64*)&As[row * LDA + sc8 * 8 + 4] = pack4(v1.x, v1.y, v1.z, v1.w);
      } else {
        L16 va = *(const L16*)((const u16*)Ap + (size_t)(m0 + row) * 384 + kt + sc8 * 8);
        *(u64*)&As[row * LDA + sc8 * 8]     = va.lo;
        *(u64*)&As[row * LDA + sc8 * 8 + 4] = va.hi;
      }
      if constexpr (BF32) {
        const float4* s = (const float4*)((const float*)Bp + (size_t)(n0 + row) * 384 + kt + sc8 * 8);
        float4 v0 = s[0], v1 = s[1];
        *(u64*)&Bs[row * LDA + sc8 * 8]     = pack4(v0.x, v0.y, v0.z, v0.w);
        *(u64*)&Bs[row * LDA + sc8 * 8 + 4] = pack4(v1.x, v1.y, v1.z, v1.w);
      } else {
        L16 vb = *(const L16*)((const u16*)Bp + (size_t)(n0 + row) * 384 + kt + sc8 * 8);
        *(u64*)&Bs[row * LDA + sc8 * 8]     = vb.lo;
        *(u64*)&Bs[row * LDA + sc8 * 8 + 4] = vb.hi;
      }
    }
    __syncthreads();
    #pragma unroll
    for (int kc = 0; kc < 64; kc += 32) {
      FragAB af[4], bf[4];
      #pragma unroll
      for (int i = 0; i < 4; ++i) {
        int ra = (wm * 64 + i * 16 + l15) * LDA + kc + q * 8;
        af[i].q[0] = *(const u64*)&As[ra];
        af[i].q[1] = *(const u64*)&As[ra + 4];
        int rb = (wn * 64 + i * 16 + l15) * LDA + kc + q * 8;
        bf[i].q[0] = *(const u64*)&Bs[rb];
        bf[i].q[1] = *(const u64*)&Bs[rb + 4];
      }
      #pragma unroll
      for (int i = 0; i < 4; ++i)
        #pragma unroll
        for (int j = 0; j < 4; ++j)
          acc[i][j] = __builtin_amdgcn_mfma_f32_16x16x32_bf16(af[i].s, bf[j].s, acc[i][j], 0, 0, 0);
    }
  }
}

#define GEMM_PROLOGUE() \
  __shared__ __align__(16) u16 S[2 * 128 * LDA]; \
  u16* As = S; u16* Bs = S + 128 * LDA; \
  floatx4 acc[4][4]; \
  { floatx4 zv = {0.f, 0.f, 0.f, 0.f}; \
    _Pragma("unroll") for (int i = 0; i < 4; ++i) \
      _Pragma("unroll") for (int j = 0; j < 4; ++j) acc[i][j] = zv; } \
  const int tid = threadIdx.x; \
  const int lane = tid & 63, wv = tid >> 6; \
  const int wm = wv & 1, wn = wv >> 1, q = lane >> 4, l15 = lane & 15; \
  (void)lane;

// coalesced tile store: S[128][TS] bf16 -> dst rows (row stride 384 u16), 256B/32-lane
__device__ __forceinline__ void tile_store(const u16* S, u16* dst, int m0) {
  const int tid = threadIdx.x;
  const int col = (tid & 31) * 4, rowo = tid >> 5;
  #pragma unroll
  for (int rr = 0; rr < 16; ++rr) {
    int row = rr * 8 + rowo;
    *(u64*)(dst + (size_t)(m0 + row) * 384 + col) = *(const u64*)&S[row * TS + col];
  }
}

// GEMM1: h(bf16) @ lin_w^T(fp32) + lin_b -> xx (n<384), z (n>=384), bf16 channel-last
__global__ __launch_bounds__(256) void k_gemm_lin(const u16* __restrict__ A,
                                                  const float* __restrict__ Bw,
                                                  const float* __restrict__ bias,
                                                  u16* __restrict__ xx, u16* __restrict__ z) {
  GEMM_PROLOGUE();
  int m0 = blockIdx.y * 128, n0 = blockIdx.x * 128;   // consecutive blocks share A-tile (L2 reuse)
  gemm_ml<false, true>(A, Bw, m0, n0, As, Bs, acc);
  __syncthreads();
  #pragma unroll
  for (int i = 0; i < 4; ++i)
    #pragma unroll
    for (int j = 0; j < 4; ++j) {
      int nl = wn * 64 + j * 16 + l15;
      float bb = bias[n0 + nl];
      #pragma unroll
      for (int r = 0; r < 4; ++r) {
        int ml = wm * 64 + i * 16 + q * 4 + r;
        S[ml * TS + nl] = f2bf(acc[i][j][r] + bb);
      }
    }
  __syncthreads();
  u16* dst = (n0 < 384) ? (xx + n0) : (z + (n0 - 384));
  tile_store(S, dst, m0);
}

// GEMM2: freq_embed(fp32) @ tok_w^T(fp32) + tok_b -> gelu -> wave gain g (bf16)
__global__ __launch_bounds__(256) void k_gemm_tok(const float* __restrict__ A,
                                                  const float* __restrict__ Bw,
                                                  const float* __restrict__ bias,
                                                  const float* __restrict__ cs,
                                                  const float* __restrict__ al,
                                                  u16* __restrict__ g) {
  GEMM_PROLOGUE();
  int m0 = blockIdx.y * 128, n0 = blockIdx.x * 128;   // consecutive blocks share A-tile
  gemm_ml<true, true>(A, Bw, m0, n0, As, Bs, acc);
  const float c0 = cs[0], a0 = al[0];
  const float sc = (1.0f / (c0 + 1e-8f)) * (1.0f + 0.5f * a0);
  __syncthreads();
  #pragma unroll
  for (int i = 0; i < 4; ++i)
    #pragma unroll
    for (int j = 0; j < 4; ++j) {
      int nl = wn * 64 + j * 16 + l15;
      float bb = bias[n0 + nl];
      #pragma unroll
      for (int r = 0; r < 4; ++r) {
        int ml = wm * 64 + i * 16 + q * 4 + r;
        float v = acc[i][j][r] + bb;
        float t = 0.5f * v * (1.0f + erff(v * 0.7071067811865476f));  // exact gelu
        float ct = c0 * t;
        S[ml * TS + nl] = f2bf(cosf(ct) + sinf(ct) * sc);
      }
    }
  __syncthreads();
  tile_store(S, g + n0, m0);
}

// GEMM3: out_w(fp32, M=channel) x A3(bf16, N=pixel) -> d_out[b,c,h,w] fp32 + out_b
__global__ __launch_bounds__(256) void k_gemm_out(const float* __restrict__ A,
                                                  const u16* __restrict__ Bp,
                                                  const float* __restrict__ bias,
                                                  float* __restrict__ outp) {
  GEMM_PROLOGUE();
  int m0 = blockIdx.x * 128, n0 = blockIdx.y * 128;   // consecutive blocks share B-tile (A3)
  gemm_ml<true, false>(A, Bp, m0, n0, As, Bs, acc);
  #pragma unroll
  for (int i = 0; i < 4; ++i)
    #pragma unroll
    for (int j = 0; j < 4; ++j) {
      int t = n0 + wn * 64 + j * 16 + l15;      // pixel index
      int b = t / 3136, p = t - b * 3136;
      #pragma unroll
      for (int r = 0; r < 4; ++r) {
        int m = m0 + wm * 64 + i * 16 + q * 4 + r;   // channel
        outp[((size_t)b * 384 + m) * 3136 + p] = acc[i][j][r] + bias[m];
      }
    }
}

// ---------------- DCT chain (fp32 math, bf16 storage, in-place) ----------------
// xx[b,h,w,c] -> u1[b,n,w,c] = sum_h Wd[n,h]*xx  (in-place)
__global__ __launch_bounds__(256) void k_dct_h(u16* __restrict__ xx,
                                               const float* __restrict__ Wd) {
  __shared__ float Xs[56 * 128];
  __shared__ float Ws[3136];
  const int w = blockIdx.x, cb = blockIdx.y * 128, b = blockIdx.z;
  const int tid = threadIdx.x;
  for (int i = tid; i < 3136; i += 256) Ws[i] = Wd[i];
  for (int i = tid; i < 56 * 64; i += 256) {
    int h = i >> 6, cu = i & 63;
    unsigned int p = *(const unsigned int*)(xx + ((size_t)(b * 56 + h) * 56 + w) * 384 + cb + cu * 2);
    bfp(p, Xs[h * 128 + cu * 2], Xs[h * 128 + cu * 2 + 1]);
  }
  __syncthreads();
  const int lane = tid & 63, wv = tid >> 6;
  float a0[14], a1[14];
  #pragma unroll
  for (int k = 0; k < 14; ++k) { a0[k] = 0.f; a1[k] = 0.f; }
  for (int h = 0; h < 56; ++h) {
    float x0 = Xs[h * 128 + 2 * lane];
    float x1 = Xs[h * 128 + 2 * lane + 1];
    #pragma unroll
    for (int k = 0; k < 14; ++k) {
      float wn = Ws[(wv + 4 * k) * 56 + h];
      a0[k] += wn * x0; a1[k] += wn * x1;
    }
  }
  #pragma unroll
  for (int k = 0; k < 14; ++k) {
    int n = wv + 4 * k;
    *(unsigned int*)(xx + ((size_t)(b * 56 + n) * 56 + w) * 384 + cb + 2 * lane) = packbf(a0[k], a1[k]);
  }
}

// fused: V = Wd @ u1[b,n] (over w); V *= g; y1[b,n] = Wd^T @ V (over m). In-place on u1.
__global__ __launch_bounds__(256) void k_mid(u16* __restrict__ u1,
                                             const u16* __restrict__ g,
                                             const float* __restrict__ Wd) {
  __shared__ float Us[56 * 64];
  __shared__ float Vs[56 * 64];
  __shared__ float Ws[3136];
  const int n = blockIdx.x, cb = blockIdx.y * 64, b = blockIdx.z;
  const int tid = threadIdx.x;
  for (int i = tid; i < 3136; i += 256) Ws[i] = Wd[i];
  for (int i = tid; i < 56 * 32; i += 256) {
    int ww = i >> 5, cu = i & 31;
    unsigned int p = *(const unsigned int*)(u1 + ((size_t)(b * 56 + n) * 56 + ww) * 384 + cb + cu * 2);
    bfp(p, Us[ww * 64 + cu * 2], Us[ww * 64 + cu * 2 + 1]);
  }
  __syncthreads();
  const int lane = tid & 63, wv = tid >> 6;
  {
    float a[14];
    #pragma unroll
    for (int k = 0; k < 14; ++k) a[k] = 0.f;
    for (int ww = 0; ww < 56; ++ww) {
      float xv = Us[ww * 64 + lane];
      #pragma unroll
      for (int k = 0; k < 14; ++k)
        a[k] += Ws[(wv + 4 * k) * 56 + ww] * xv;
    }
    #pragma unroll
    for (int k = 0; k < 14; ++k) Vs[(wv + 4 * k) * 64 + lane] = a[k];
  }
  __syncthreads();
  for (int i = tid; i < 56 * 32; i += 256) {
    int m = i >> 5, cu = i & 31;
    unsigned int p = *(const unsigned int*)(g + ((size_t)(b * 56 + n) * 56 + m) * 384 + cb + cu * 2);
    float g0, g1; bfp(p, g0, g1);
    Vs[m * 64 + cu * 2]     *= g0;
    Vs[m * 64 + cu * 2 + 1] *= g1;
  }
  __syncthreads();
  {
    float a[14];
    #pragma unroll
    for (int k = 0; k < 14; ++k) a[k] = 0.f;
    for (int m = 0; m < 56; ++m) {
      float xv = Vs[m * 64 + lane];
      #pragma unroll
      for (int k = 0; k < 14; ++k)
        a[k] += Ws[m * 56 + (wv + 4 * k)] * xv;   // Wd[m, yy]
    }
    #pragma unroll
    for (int k = 0; k < 14; ++k) {
      int yy = wv + 4 * k;
      u1[((size_t)(b * 56 + n) * 56 + yy) * 384 + cb + lane] = f2bf(a[k]);
    }
  }
}

// y1[b,n,yy,c] -> y2[b,x,yy,c] = sum_n Wd[n,x]*y1  (in-place)
__global__ __launch_bounds__(256) void k_idct_h(u16* __restrict__ y1,
                                                const float* __restrict__ Wd) {
  __shared__ float Ys[56 * 128];
  __shared__ float Ws[3136];
  const int yy = blockIdx.x, cb = blockIdx.y * 128, b = blockIdx.z;
  const int tid = threadIdx.x;
  for (int i = tid; i < 3136; i += 256) Ws[i] = Wd[i];
  for (int i = tid; i < 56 * 64; i += 256) {
    int nn = i >> 6, cu = i & 63;
    unsigned int p = *(const unsigned int*)(y1 + ((size_t)(b * 56 + nn) * 56 + yy) * 384 + cb + cu * 2);
    bfp(p, Ys[nn * 128 + cu * 2], Ys[nn * 128 + cu * 2 + 1]);
  }
  __syncthreads();
  const int lane = tid & 63, wv = tid >> 6;
  float a0[14], a1[14];
  #pragma unroll
  for (int k = 0; k < 14; ++k) { a0[k] = 0.f; a1[k] = 0.f; }
  for (int nn = 0; nn < 56; ++nn) {
    float x0 = Ys[nn * 128 + 2 * lane];
    float x1 = Ys[nn * 128 + 2 * lane + 1];
    #pragma unroll
    for (int k = 0; k < 14; ++k) {
      float wn = Ws[nn * 56 + (wv + 4 * k)];   // Wd[n, x]
      a0[k] += wn * x0; a1[k] += wn * x1;
    }
  }
  #pragma unroll
  for (int k = 0; k < 14; ++k) {
    int x = wv + 4 * k;
    *(unsigned int*)(y1 + ((size_t)(b * 56 + x) * 56 + yy) * 384 + cb + 2 * lane) = packbf(a0[k], a1[k]);
  }
}

// ---------------- LayerNorm + SiLU gate -> bf16 A3 (in-place over y2) ----------------
__global__ __launch_bounds__(256) void k_ln(u16* __restrict__ y2,
                                            const u16* __restrict__ z,
                                            const float* __restrict__ lgm,
                                            const float* __restrict__ lbt) {
  const int t = blockIdx.x * 4 + (threadIdx.x >> 6);
  const int lane = threadIdx.x & 63;
  u16* yr = y2 + (size_t)t * 384;
  const u16* zr = z + (size_t)t * 384;
  float v[6]; float s = 0.f, s2 = 0.f;
  #pragma unroll
  for (int k = 0; k < 3; ++k) {
    unsigned int p = *(const unsigned int*)(yr + 2 * lane + 128 * k);
    float f0, f1; bfp(p, f0, f1);
    v[2 * k] = f0; v[2 * k + 1] = f1;
    s += f0 + f1; s2 += f0 * f0 + f1 * f1;
  }
  #pragma unroll
  for (int off = 32; off >= 1; off >>= 1) {
    s  += __shfl_xor(s, off, 64);
    s2 += __shfl_xor(s2, off, 64);
  }
  const float mu  = s * (1.0f / 384.0f);
  const float var = s2 * (1.0f / 384.0f) - mu * mu;
  const float inv = rsqrtf(var + 1e-5f);
  #pragma unroll
  for (int k = 0; k < 3; ++k) {
    int c = 2 * lane + 128 * k;
    float z0, z1;
    bfp(*(const unsigned int*)(zr + c), z0, z1);
    float yn0 = (v[2 * k]     - mu) * inv * lgm[c]     + lbt[c];
    float yn1 = (v[2 * k + 1] - mu) * inv * lgm[c + 1] + lbt[c + 1];
    float ga0 = z0 / (1.0f + expf(-z0));
    float ga1 = z1 / (1.0f + expf(-z1));
    *(unsigned int*)(yr + c) = packbf(yn0 * ga0, yn1 * ga1);
  }
}

// ---------------- launch ----------------
extern "C" void kernel_launch(void* const* d_in, const int* in_sizes, int n_in,
                              void* d_out, int out_size, void* d_ws, size_t ws_size,
                              hipStream_t stream) {
  const float* x     = (const float*)d_in[0];
  const float* fe    = (const float*)d_in[1];
  const float* dw_w  = (const float*)d_in[2];
  const float* dw_b  = (const float*)d_in[3];
  const float* lin_w = (const float*)d_in[4];
  const float* lin_b = (const float*)d_in[5];
  const float* tok_w = (const float*)d_in[6];
  const float* tok_b = (const float*)d_in[7];
  const float* ln_g  = (const float*)d_in[8];
  const float* ln_b  = (const float*)d_in[9];
  const float* out_w = (const float*)d_in[10];
  const float* out_b = (const float*)d_in[11];
  const float* cs    = (const float*)d_in[12];
  const float* al    = (const float*)d_in[13];
  float* outp = (float*)d_out;
  char* ws = (char*)d_ws;

  float* Wd = (float*)(ws + 0);                        // 12,544 B
  u16* SA = (u16*)(ws + 16384);                        // h, then g
  u16* SB = (u16*)(ws + 16384 + 38535168);             // xx -> u1 -> y1 -> y2 -> A3 (in-place chain)
  u16* SC = (u16*)(ws + 16384 + 2 * (size_t)38535168); // z

  k_dctmat<<<dim3(13), dim3(256), 0, stream>>>(Wd);
  k_conv<<<dim3(56, 6, 16), dim3(256), 0, stream>>>(x, dw_w, dw_b, SA);          // h in SA
  k_gemm_lin<<<dim3(6, 392), dim3(256), 0, stream>>>(SA, lin_w, lin_b, SB, SC);  // xx in SB, z in SC
  k_gemm_tok<<<dim3(3, 392), dim3(256), 0, stream>>>(fe, tok_w, tok_b, cs, al, SA); // g in SA
  k_dct_h<<<dim3(56, 3, 16), dim3(256), 0, stream>>>(SB, Wd);                    // xx -> u1
  k_mid<<<dim3(56, 6, 16), dim3(256), 0, stream>>>(SB, SA, Wd);                  // u1,g -> y1
  k_idct_h<<<dim3(56, 3, 16), dim3(256), 0, stream>>>(SB, Wd);                   // y1 -> y2
  k_ln<<<dim3(12544), dim3(256), 0, stream>>>(SB, SC, ln_g, ln_b);               // y2,z -> A3
  k_gemm_out<<<dim3(3, 392), dim3(256), 0, stream>>>(out_w, SB, out_b, outp);
}